// Round 4
// baseline (173.022 us; speedup 1.0000x reference)
//
#include <hip/hip_runtime.h>

#define NN 768
#define FD 256
#define HD 128

__device__ __forceinline__ float relu(float x) { return x > 0.f ? x : 0.f; }

// Contribution of 4 k-slots: sum relu(a+b)*w
__device__ __forceinline__ float rdot(float4 a, float4 b, float4 w) {
    float s = relu(a.x + b.x) * w.x;
    s = fmaf(relu(a.y + b.y), w.y, s);
    s = fmaf(relu(a.z + b.z), w.z, s);
    s = fmaf(relu(a.w + b.w), w.w, s);
    return s;
}

// K1: blocks 0..191 handle rows 4b..4b+3: dinv[i] and t1D[i,k] = dinv[i]*(x@w1)[i,k].
//     block 192 computes c[k] = temb[t]@we1[2H:] + be1.
__global__ void k_prep(const float* __restrict__ x, const float* __restrict__ adj,
                       const float* __restrict__ w1, const float* __restrict__ temb,
                       const float* __restrict__ we1, const float* __restrict__ be1,
                       const int* __restrict__ tptr, float* __restrict__ dinv,
                       float* __restrict__ cvec, float* __restrict__ t1D) {
    int b = blockIdx.x, tid = threadIdx.x;
    if (b == 192) {
        __shared__ float ts[HD];
        if (tid < HD) ts[tid] = temb[tptr[0] * HD + tid];
        __syncthreads();
        if (tid < HD) {
            float acc = be1[tid];
            for (int m = 0; m < HD; ++m) acc += ts[m] * we1[(2 * HD + m) * HD + tid];
            cvec[tid] = acc;
        }
        return;
    }
    int i0 = b * 4;
    __shared__ float xs[4][FD];
    __shared__ float sdi[4];
    {   // stage 4 x-rows (float4)
        int row = tid >> 6, m4 = tid & 63;
        *(float4*)&xs[row][m4 * 4] = *(const float4*)&x[(i0 + row) * FD + m4 * 4];
    }
    {   // dinv: wave w sums adj row i0+w
        int w = tid >> 6, l = tid & 63;
        float s = 0.f;
        for (int c4 = l; c4 < NN / 4; c4 += 64) {
            float4 a = *(const float4*)&adj[(i0 + w) * NN + c4 * 4];
            s += a.x + a.y + a.z + a.w;
        }
#pragma unroll
        for (int off = 32; off > 0; off >>= 1) s += __shfl_down(s, off, 64);
        if (l == 0) { float d = rsqrtf(s + 1.f); dinv[i0 + w] = d; sdi[w] = d; }
    }
    __syncthreads();
    int ty = tid >> 7, k = tid & 127;
    float aa = 0.f, ab = 0.f;
#pragma unroll 2
    for (int m4 = 0; m4 < FD / 4; ++m4) {
        float4 xa = *(float4*)&xs[ty][m4 * 4];
        float4 xb = *(float4*)&xs[ty + 2][m4 * 4];
        float w0 = w1[(m4 * 4 + 0) * HD + k];
        float w1v = w1[(m4 * 4 + 1) * HD + k];
        float w2v = w1[(m4 * 4 + 2) * HD + k];
        float w3 = w1[(m4 * 4 + 3) * HD + k];
        aa = fmaf(xa.x, w0, fmaf(xa.y, w1v, fmaf(xa.z, w2v, fmaf(xa.w, w3, aa))));
        ab = fmaf(xb.x, w0, fmaf(xb.y, w1v, fmaf(xb.z, w2v, fmaf(xb.w, w3, ab))));
    }
    t1D[(i0 + ty) * HD + k] = sdi[ty] * aa;
    t1D[(i0 + ty + 2) * HD + k] = sdi[ty + 2] * ab;
}

// K2: rows 4b..4b+3: h1 = relu(dinv[i]*(adj_row @ tinD + tinD[i])); t2D = dinv[i]*(h1 @ w2)
__global__ void k_gcn_w(const float* __restrict__ adj, const float* __restrict__ dinv,
                        const float* __restrict__ tin, const float* __restrict__ w2,
                        float* __restrict__ outD) {
    int b = blockIdx.x, tid = threadIdx.x;
    int i0 = b * 4, ty = tid >> 7, k = tid & 127;
    int ra = i0 + ty, rb = i0 + ty + 2;
    __shared__ float g[4][HD];
    float aa = 0.f, ab = 0.f;
#pragma unroll 2
    for (int j4 = 0; j4 < NN / 4; ++j4) {
        float4 a4 = *(const float4*)&adj[ra * NN + j4 * 4];
        float4 b4 = *(const float4*)&adj[rb * NN + j4 * 4];
        float t0 = tin[(j4 * 4 + 0) * HD + k];
        float t1 = tin[(j4 * 4 + 1) * HD + k];
        float t2 = tin[(j4 * 4 + 2) * HD + k];
        float t3 = tin[(j4 * 4 + 3) * HD + k];
        aa = fmaf(a4.x, t0, fmaf(a4.y, t1, fmaf(a4.z, t2, fmaf(a4.w, t3, aa))));
        ab = fmaf(b4.x, t0, fmaf(b4.y, t1, fmaf(b4.z, t2, fmaf(b4.w, t3, ab))));
    }
    aa += tin[ra * HD + k];  // self loop (dinv[j] already folded into tin)
    ab += tin[rb * HD + k];
    g[ty][k] = relu(dinv[ra] * aa);
    g[ty + 2][k] = relu(dinv[rb] * ab);
    __syncthreads();
    float ca = 0.f, cb = 0.f;
#pragma unroll 2
    for (int m4 = 0; m4 < HD / 4; ++m4) {
        float4 ga = *(float4*)&g[ty][m4 * 4];
        float4 gb = *(float4*)&g[ty + 2][m4 * 4];
        float w0 = w2[(m4 * 4 + 0) * HD + k];
        float w1v = w2[(m4 * 4 + 1) * HD + k];
        float w2v = w2[(m4 * 4 + 2) * HD + k];
        float w3 = w2[(m4 * 4 + 3) * HD + k];
        ca = fmaf(ga.x, w0, fmaf(ga.y, w1v, fmaf(ga.z, w2v, fmaf(ga.w, w3, ca))));
        cb = fmaf(gb.x, w0, fmaf(gb.y, w1v, fmaf(gb.z, w2v, fmaf(gb.w, w3, cb))));
    }
    outD[ra * HD + k] = dinv[ra] * ca;
    outD[rb * HD + k] = dinv[rb] * cb;
}

// K3: rows 4b..4b+3: h2 = relu(dinv[i]*(adj_row @ t2D + t2D[i]));
//     p = h2 @ we1[:H] + c ; q = h2 @ we1[H:2H]
__global__ void k_gcn_pq(const float* __restrict__ adj, const float* __restrict__ dinv,
                         const float* __restrict__ tin, const float* __restrict__ we1,
                         const float* __restrict__ cvec, float* __restrict__ p,
                         float* __restrict__ q) {
    int b = blockIdx.x, tid = threadIdx.x;
    int i0 = b * 4, ty = tid >> 7, k = tid & 127;
    int ra = i0 + ty, rb = i0 + ty + 2;
    __shared__ float g[4][HD];
    float aa = 0.f, ab = 0.f;
#pragma unroll 2
    for (int j4 = 0; j4 < NN / 4; ++j4) {
        float4 a4 = *(const float4*)&adj[ra * NN + j4 * 4];
        float4 b4 = *(const float4*)&adj[rb * NN + j4 * 4];
        float t0 = tin[(j4 * 4 + 0) * HD + k];
        float t1 = tin[(j4 * 4 + 1) * HD + k];
        float t2 = tin[(j4 * 4 + 2) * HD + k];
        float t3 = tin[(j4 * 4 + 3) * HD + k];
        aa = fmaf(a4.x, t0, fmaf(a4.y, t1, fmaf(a4.z, t2, fmaf(a4.w, t3, aa))));
        ab = fmaf(b4.x, t0, fmaf(b4.y, t1, fmaf(b4.z, t2, fmaf(b4.w, t3, ab))));
    }
    aa += tin[ra * HD + k];
    ab += tin[rb * HD + k];
    g[ty][k] = relu(dinv[ra] * aa);
    g[ty + 2][k] = relu(dinv[rb] * ab);
    __syncthreads();
    float pa = cvec[k], pb = pa, qa = 0.f, qb = 0.f;
    for (int m4 = 0; m4 < HD / 4; ++m4) {
        float4 ga = *(float4*)&g[ty][m4 * 4];
        float4 gb = *(float4*)&g[ty + 2][m4 * 4];
#pragma unroll
        for (int c = 0; c < 4; ++c) {
            int m = m4 * 4 + c;
            float wp = we1[m * HD + k];
            float wq = we1[(HD + m) * HD + k];
            float gav = (&ga.x)[c], gbv = (&gb.x)[c];
            pa = fmaf(gav, wp, pa); qa = fmaf(gav, wq, qa);
            pb = fmaf(gbv, wp, pb); qb = fmaf(gbv, wq, qb);
        }
    }
    p[ra * HD + k] = pa; q[ra * HD + k] = qa;
    p[rb * HD + k] = pb; q[rb * HD + k] = qb;
}

// K4: 32x32 tile pairs (bi<=bj), 300 blocks; 2x2 outputs per thread, both directions.
__global__ void k_pair(const float* __restrict__ p, const float* __restrict__ q,
                       const float* __restrict__ we2, const float* __restrict__ be2,
                       float* __restrict__ out) {
    int t = blockIdx.x;
    int bj = (int)((sqrtf(8.f * t + 1.f) - 1.f) * 0.5f);
    while ((bj + 1) * (bj + 2) / 2 <= t) ++bj;
    while (bj * (bj + 1) / 2 > t) --bj;
    int bi = t - bj * (bj + 1) / 2;
    int i0 = bi * 32, j0 = bj * 32;
    __shared__ float spi[32][68], sqi[32][68], spj[32][68], sqj[32][68];
    __shared__ float w2s[HD];
    int tid = threadIdx.x;
    int tx = tid & 15, ty = tid >> 4;
    if (tid < HD) w2s[tid] = we2[tid];
    float accij[2][2] = {{0.f, 0.f}, {0.f, 0.f}};
    float accji[2][2] = {{0.f, 0.f}, {0.f, 0.f}};
    for (int h = 0; h < 2; ++h) {
        __syncthreads();
        int kb = h * 64;
        for (int idx = tid; idx < 512; idx += 256) {
            int r = idx >> 4, c4 = idx & 15;
            *(float4*)&spi[r][c4 * 4] = *(const float4*)&p[(i0 + r) * HD + kb + c4 * 4];
            *(float4*)&sqi[r][c4 * 4] = *(const float4*)&q[(i0 + r) * HD + kb + c4 * 4];
            *(float4*)&spj[r][c4 * 4] = *(const float4*)&p[(j0 + r) * HD + kb + c4 * 4];
            *(float4*)&sqj[r][c4 * 4] = *(const float4*)&q[(j0 + r) * HD + kb + c4 * 4];
        }
        __syncthreads();
#pragma unroll 4
        for (int k4 = 0; k4 < 16; ++k4) {
            float4 w = *(float4*)&w2s[kb + k4 * 4];
            float4 Pi0 = *(float4*)&spi[2 * ty + 0][k4 * 4];
            float4 Pi1 = *(float4*)&spi[2 * ty + 1][k4 * 4];
            float4 Qi0 = *(float4*)&sqi[2 * ty + 0][k4 * 4];
            float4 Qi1 = *(float4*)&sqi[2 * ty + 1][k4 * 4];
            float4 Pj0 = *(float4*)&spj[2 * tx + 0][k4 * 4];
            float4 Pj1 = *(float4*)&spj[2 * tx + 1][k4 * 4];
            float4 Qj0 = *(float4*)&sqj[2 * tx + 0][k4 * 4];
            float4 Qj1 = *(float4*)&sqj[2 * tx + 1][k4 * 4];
            accij[0][0] += rdot(Pi0, Qj0, w); accji[0][0] += rdot(Pj0, Qi0, w);
            accij[0][1] += rdot(Pi0, Qj1, w); accji[0][1] += rdot(Pj1, Qi0, w);
            accij[1][0] += rdot(Pi1, Qj0, w); accji[1][0] += rdot(Pj0, Qi1, w);
            accij[1][1] += rdot(Pi1, Qj1, w); accji[1][1] += rdot(Pj1, Qi1, w);
        }
    }
    float bias = be2[0];
#pragma unroll
    for (int e = 0; e < 2; ++e)
#pragma unroll
        for (int f = 0; f < 2; ++f) {
            int i = i0 + 2 * ty + e, j = j0 + 2 * tx + f;
            float lij = accij[e][f] + bias, lji = accji[e][f] + bias;
            float v = 0.5f * (1.f / (1.f + __expf(-lij)) + 1.f / (1.f + __expf(-lji)));
            out[i * NN + j] = v;
            out[j * NN + i] = v;
        }
}

extern "C" void kernel_launch(void* const* d_in, const int* in_sizes, int n_in,
                              void* d_out, int out_size, void* d_ws, size_t ws_size,
                              hipStream_t stream) {
    const float* x    = (const float*)d_in[0];
    const float* adj  = (const float*)d_in[1];
    const float* w1   = (const float*)d_in[2];
    const float* w2   = (const float*)d_in[3];
    const float* temb = (const float*)d_in[4];
    const float* we1  = (const float*)d_in[5];
    const float* be1  = (const float*)d_in[6];
    const float* we2  = (const float*)d_in[7];
    const float* be2  = (const float*)d_in[8];
    const int* tptr   = (const int*)d_in[9];
    float* out        = (float*)d_out;

    float* ws   = (float*)d_ws;
    float* dinv = ws;               // 768
    float* c    = ws + 768;         // 128
    float* A    = ws + 1024;        // 768*128  t1D, later p
    float* B    = A + NN * HD;      // 768*128  t2D
    float* C    = B + NN * HD;      // 768*128  q

    k_prep  <<<193, 256, 0, stream>>>(x, adj, w1, temb, we1, be1, tptr, dinv, c, A);
    k_gcn_w <<<192, 256, 0, stream>>>(adj, dinv, A, w2, B);
    k_gcn_pq<<<192, 256, 0, stream>>>(adj, dinv, B, we1, c, A, C);
    k_pair  <<<300, 256, 0, stream>>>(A, C, we2, be2, out);
}

// Round 5
// 140.204 us; speedup vs baseline: 1.2341x; 1.2341x over previous
//
#include <hip/hip_runtime.h>

#define NN 768
#define FD 256
#define HD 128

__device__ __forceinline__ float relu(float x) { return x > 0.f ? x : 0.f; }

__device__ __forceinline__ float rdot(float4 a, float4 b, float4 w) {
    float s = relu(a.x + b.x) * w.x;
    s = fmaf(relu(a.y + b.y), w.y, s);
    s = fmaf(relu(a.z + b.z), w.z, s);
    s = fmaf(relu(a.w + b.w), w.w, s);
    return s;
}

// K1: blocks 0..255 -> rows 3b..3b+2: dinv[i]; t1D[i,k] = dinv[i]*(x@w1)[i,k].
//     block 256 -> c[k] = temb[t]@we1[2H:] + be1.
__global__ __launch_bounds__(384) void k_prep(
        const float* __restrict__ x, const float* __restrict__ adj,
        const float* __restrict__ w1, const float* __restrict__ temb,
        const float* __restrict__ we1, const float* __restrict__ be1,
        const int* __restrict__ tptr, float* __restrict__ dinv,
        float* __restrict__ cvec, float* __restrict__ t1D) {
    int b = blockIdx.x, tid = threadIdx.x;
    if (b == 256) {
        __shared__ float ts[HD];
        if (tid < HD) ts[tid] = temb[tptr[0] * HD + tid];
        __syncthreads();
        if (tid < HD) {
            float a0 = be1[tid], a1 = 0.f, a2 = 0.f, a3 = 0.f;
            for (int m = 0; m < HD; m += 4) {
                float w0 = we1[(2 * HD + m + 0) * HD + tid];
                float w1v = we1[(2 * HD + m + 1) * HD + tid];
                float w2v = we1[(2 * HD + m + 2) * HD + tid];
                float w3 = we1[(2 * HD + m + 3) * HD + tid];
                a0 = fmaf(ts[m + 0], w0, a0); a1 = fmaf(ts[m + 1], w1v, a1);
                a2 = fmaf(ts[m + 2], w2v, a2); a3 = fmaf(ts[m + 3], w3, a3);
            }
            cvec[tid] = (a0 + a1) + (a2 + a3);
        }
        return;
    }
    int i0 = b * 3;
    __shared__ float xs[3][FD];
    __shared__ float sdi[3];
    if (tid < 192) {  // stage 3 x-rows as float4
        int row = tid >> 6, m4 = tid & 63;
        *(float4*)&xs[row][m4 * 4] = *(const float4*)&x[(i0 + row) * FD + m4 * 4];
    }
    {   // dinv: waves 0..2 sum adj rows
        int w = tid >> 6, l = tid & 63;
        if (w < 3) {
            float4 c0 = *(const float4*)&adj[(i0 + w) * NN + l * 4];
            float4 c1 = *(const float4*)&adj[(i0 + w) * NN + (l + 64) * 4];
            float4 c2 = *(const float4*)&adj[(i0 + w) * NN + (l + 128) * 4];
            float s = (c0.x + c0.y + c0.z + c0.w) + (c1.x + c1.y + c1.z + c1.w)
                    + (c2.x + c2.y + c2.z + c2.w);
#pragma unroll
            for (int off = 32; off > 0; off >>= 1) s += __shfl_down(s, off, 64);
            if (l == 0) { float d = rsqrtf(s + 1.f); dinv[i0 + w] = d; sdi[w] = d; }
        }
    }
    __syncthreads();
    int r = tid >> 7, k = tid & 127;
    float a0 = 0.f, a1 = 0.f, a2 = 0.f, a3 = 0.f;
    for (int g = 0; g < FD; g += 16) {
        float wv[16];
#pragma unroll
        for (int u = 0; u < 16; ++u) wv[u] = w1[(g + u) * HD + k];
#pragma unroll
        for (int u = 0; u < 16; ++u) {
            float xv = xs[r][g + u];
            if ((u & 3) == 0) a0 = fmaf(xv, wv[u], a0);
            else if ((u & 3) == 1) a1 = fmaf(xv, wv[u], a1);
            else if ((u & 3) == 2) a2 = fmaf(xv, wv[u], a2);
            else a3 = fmaf(xv, wv[u], a3);
        }
    }
    t1D[(i0 + r) * HD + k] = sdi[r] * ((a0 + a1) + (a2 + a3));
}

// Shared aggregation: acc[k] for row i = sum_j adj[i,j]*tinD[j,k]  (deep-unrolled)
__device__ __forceinline__ float agg_row(const float* __restrict__ arow,
                                         const float* __restrict__ tin, int k) {
    float a0 = 0.f, a1 = 0.f, a2 = 0.f, a3 = 0.f;
    for (int g = 0; g < NN; g += 32) {
        float4 av[8];
        float tv[8][4];
#pragma unroll
        for (int u = 0; u < 8; ++u) av[u] = *(const float4*)&arow[g + u * 4];
#pragma unroll
        for (int u = 0; u < 8; ++u) {
#pragma unroll
            for (int c = 0; c < 4; ++c) tv[u][c] = tin[(g + u * 4 + c) * HD + k];
        }
#pragma unroll
        for (int u = 0; u < 8; ++u) {
            a0 = fmaf(av[u].x, tv[u][0], a0);
            a1 = fmaf(av[u].y, tv[u][1], a1);
            a2 = fmaf(av[u].z, tv[u][2], a2);
            a3 = fmaf(av[u].w, tv[u][3], a3);
        }
    }
    return (a0 + a1) + (a2 + a3);
}

// K2: rows 3b..3b+2: h1 = relu(dinv[i]*(agg + tinD[i])); outD = dinv[i]*(h1@w2)
__global__ __launch_bounds__(384) void k_gcn_w(
        const float* __restrict__ adj, const float* __restrict__ dinv,
        const float* __restrict__ tin, const float* __restrict__ w2,
        float* __restrict__ outD) {
    int b = blockIdx.x, tid = threadIdx.x;
    int r = tid >> 7, k = tid & 127;
    int i = b * 3 + r;
    __shared__ float gs[3][HD];
    float acc = agg_row(adj + i * NN, tin, k) + tin[i * HD + k];
    gs[r][k] = relu(dinv[i] * acc);
    __syncthreads();
    float a0 = 0.f, a1 = 0.f, a2 = 0.f, a3 = 0.f;
    for (int g = 0; g < HD; g += 16) {
        float wv[16];
#pragma unroll
        for (int u = 0; u < 16; ++u) wv[u] = w2[(g + u) * HD + k];
#pragma unroll
        for (int u = 0; u < 16; ++u) {
            float hv = gs[r][g + u];
            if ((u & 3) == 0) a0 = fmaf(hv, wv[u], a0);
            else if ((u & 3) == 1) a1 = fmaf(hv, wv[u], a1);
            else if ((u & 3) == 2) a2 = fmaf(hv, wv[u], a2);
            else a3 = fmaf(hv, wv[u], a3);
        }
    }
    outD[i * HD + k] = dinv[i] * ((a0 + a1) + (a2 + a3));
}

// K3: rows 3b..3b+2: h2 = relu(dinv[i]*(agg + tinD[i])); p = h2@we1[:H]+c; q = h2@we1[H:2H]
__global__ __launch_bounds__(384) void k_gcn_pq(
        const float* __restrict__ adj, const float* __restrict__ dinv,
        const float* __restrict__ tin, const float* __restrict__ we1,
        const float* __restrict__ cvec, float* __restrict__ p, float* __restrict__ q) {
    int b = blockIdx.x, tid = threadIdx.x;
    int r = tid >> 7, k = tid & 127;
    int i = b * 3 + r;
    __shared__ float gs[3][HD];
    float acc = agg_row(adj + i * NN, tin, k) + tin[i * HD + k];
    gs[r][k] = relu(dinv[i] * acc);
    __syncthreads();
    float pa = cvec[k], p1 = 0.f, qa = 0.f, q1 = 0.f;
    for (int g = 0; g < HD; g += 8) {
        float wp[8], wq[8];
#pragma unroll
        for (int u = 0; u < 8; ++u) {
            wp[u] = we1[(g + u) * HD + k];
            wq[u] = we1[(HD + g + u) * HD + k];
        }
#pragma unroll
        for (int u = 0; u < 8; ++u) {
            float hv = gs[r][g + u];
            if (u & 1) { p1 = fmaf(hv, wp[u], p1); q1 = fmaf(hv, wq[u], q1); }
            else       { pa = fmaf(hv, wp[u], pa); qa = fmaf(hv, wq[u], qa); }
        }
    }
    p[i * HD + k] = pa + p1;
    q[i * HD + k] = qa + q1;
}

// K4: 32x32 tile pairs (bi<=bj), 300 blocks; 2x2 outputs per thread, both directions.
__global__ __launch_bounds__(256) void k_pair(
        const float* __restrict__ p, const float* __restrict__ q,
        const float* __restrict__ we2, const float* __restrict__ be2,
        float* __restrict__ out) {
    int t = blockIdx.x;
    int bj = (int)((sqrtf(8.f * t + 1.f) - 1.f) * 0.5f);
    while ((bj + 1) * (bj + 2) / 2 <= t) ++bj;
    while (bj * (bj + 1) / 2 > t) --bj;
    int bi = t - bj * (bj + 1) / 2;
    int i0 = bi * 32, j0 = bj * 32;
    __shared__ float spi[32][68], sqi[32][68], spj[32][68], sqj[32][68];
    __shared__ float w2s[HD];
    int tid = threadIdx.x;
    int tx = tid & 15, ty = tid >> 4;
    if (tid < HD) w2s[tid] = we2[tid];
    float accij[2][2] = {{0.f, 0.f}, {0.f, 0.f}};
    float accji[2][2] = {{0.f, 0.f}, {0.f, 0.f}};
    for (int h = 0; h < 2; ++h) {
        __syncthreads();
        int kb = h * 64;
        for (int idx = tid; idx < 512; idx += 256) {
            int r = idx >> 4, c4 = idx & 15;
            *(float4*)&spi[r][c4 * 4] = *(const float4*)&p[(i0 + r) * HD + kb + c4 * 4];
            *(float4*)&sqi[r][c4 * 4] = *(const float4*)&q[(i0 + r) * HD + kb + c4 * 4];
            *(float4*)&spj[r][c4 * 4] = *(const float4*)&p[(j0 + r) * HD + kb + c4 * 4];
            *(float4*)&sqj[r][c4 * 4] = *(const float4*)&q[(j0 + r) * HD + kb + c4 * 4];
        }
        __syncthreads();
#pragma unroll 8
        for (int k4 = 0; k4 < 16; ++k4) {
            float4 w = *(float4*)&w2s[kb + k4 * 4];
            float4 Pi0 = *(float4*)&spi[2 * ty + 0][k4 * 4];
            float4 Pi1 = *(float4*)&spi[2 * ty + 1][k4 * 4];
            float4 Qi0 = *(float4*)&sqi[2 * ty + 0][k4 * 4];
            float4 Qi1 = *(float4*)&sqi[2 * ty + 1][k4 * 4];
            float4 Pj0 = *(float4*)&spj[2 * tx + 0][k4 * 4];
            float4 Pj1 = *(float4*)&spj[2 * tx + 1][k4 * 4];
            float4 Qj0 = *(float4*)&sqj[2 * tx + 0][k4 * 4];
            float4 Qj1 = *(float4*)&sqj[2 * tx + 1][k4 * 4];
            accij[0][0] += rdot(Pi0, Qj0, w); accji[0][0] += rdot(Pj0, Qi0, w);
            accij[0][1] += rdot(Pi0, Qj1, w); accji[0][1] += rdot(Pj1, Qi0, w);
            accij[1][0] += rdot(Pi1, Qj0, w); accji[1][0] += rdot(Pj0, Qi1, w);
            accij[1][1] += rdot(Pi1, Qj1, w); accji[1][1] += rdot(Pj1, Qi1, w);
        }
    }
    float bias = be2[0];
#pragma unroll
    for (int e = 0; e < 2; ++e)
#pragma unroll
        for (int f = 0; f < 2; ++f) {
            int i = i0 + 2 * ty + e, j = j0 + 2 * tx + f;
            float lij = accij[e][f] + bias, lji = accji[e][f] + bias;
            float v = 0.5f * (1.f / (1.f + __expf(-lij)) + 1.f / (1.f + __expf(-lji)));
            out[i * NN + j] = v;
            out[j * NN + i] = v;
        }
}

extern "C" void kernel_launch(void* const* d_in, const int* in_sizes, int n_in,
                              void* d_out, int out_size, void* d_ws, size_t ws_size,
                              hipStream_t stream) {
    const float* x    = (const float*)d_in[0];
    const float* adj  = (const float*)d_in[1];
    const float* w1   = (const float*)d_in[2];
    const float* w2   = (const float*)d_in[3];
    const float* temb = (const float*)d_in[4];
    const float* we1  = (const float*)d_in[5];
    const float* be1  = (const float*)d_in[6];
    const float* we2  = (const float*)d_in[7];
    const float* be2  = (const float*)d_in[8];
    const int* tptr   = (const int*)d_in[9];
    float* out        = (float*)d_out;

    float* ws   = (float*)d_ws;
    float* dinv = ws;               // 768
    float* c    = ws + 768;         // 128
    float* A    = ws + 1024;        // 768*128  t1D, later p
    float* B    = A + NN * HD;      // 768*128  t2D
    float* C    = B + NN * HD;      // 768*128  q

    k_prep  <<<257, 384, 0, stream>>>(x, adj, w1, temb, we1, be1, tptr, dinv, c, A);
    k_gcn_w <<<256, 384, 0, stream>>>(adj, dinv, A, w2, B);
    k_gcn_pq<<<256, 384, 0, stream>>>(adj, dinv, B, we1, c, A, C);
    k_pair  <<<300, 256, 0, stream>>>(A, C, we2, be2, out);
}